// Round 6
// baseline (261.148 us; speedup 1.0000x reference)
//
#include <hip/hip_runtime.h>

#define T_FRAMES 256
#define D_IN 80
#define CCH 256
#define CCEP 222
#define FFT_N 1024
#define HOP 256
#define WINL 512
#define PF_KT 128
#define ZLEN 65536

__device__ __forceinline__ unsigned br10(unsigned x) { return __brev(x) >> 22; }

// ---- K1: conv1 (blocks 0..63) + w2/w3 transpose (blocks 64..255) + flag zeroing (block 64) ----
__global__ __launch_bounds__(512) void conv1_tr_k(const float* __restrict__ x, const float* __restrict__ w1,
                                                  const float* __restrict__ b1,
                                                  const float* __restrict__ w2, const float* __restrict__ w3,
                                                  float* __restrict__ h1,
                                                  float* __restrict__ w2t, float* __restrict__ w3t,
                                                  int* __restrict__ flags) {
  __shared__ float xs[6 * D_IN];
  int b = blockIdx.x, tid = threadIdx.x;
  if (b == 64 && tid < 384) flags[tid] = 0;
  if (b < 64) {
    int t0 = b * 4;
    for (int i = tid; i < 6 * D_IN; i += 512) {
      int r = i / D_IN, cin = i - r * D_IN;
      int tt = t0 - 1 + r;
      xs[i] = (tt >= 0 && tt < T_FRAMES) ? x[tt * D_IN + cin] : 0.f;
    }
    __syncthreads();
    if (tid < 256) {
      int c = tid;
      const float4* row4 = (const float4*)(w1 + c * 240);
      float a0 = b1[c], a1 = a0, a2 = a0, a3 = a0;
      #define ACC1(wv, cin, kk) { float _w = (wv); \
        a0 += xs[((kk) + 0) * D_IN + (cin)] * _w; \
        a1 += xs[((kk) + 1) * D_IN + (cin)] * _w; \
        a2 += xs[((kk) + 2) * D_IN + (cin)] * _w; \
        a3 += xs[((kk) + 3) * D_IN + (cin)] * _w; }
      #pragma unroll 5
      for (int g = 0; g < 20; ++g) {
        int c0 = g * 4;
        float4 wa = row4[g * 3 + 0];
        float4 wb = row4[g * 3 + 1];
        float4 wc = row4[g * 3 + 2];
        ACC1(wa.x, c0 + 0, 0) ACC1(wa.y, c0 + 0, 1) ACC1(wa.z, c0 + 0, 2) ACC1(wa.w, c0 + 1, 0)
        ACC1(wb.x, c0 + 1, 1) ACC1(wb.y, c0 + 1, 2) ACC1(wb.z, c0 + 2, 0) ACC1(wb.w, c0 + 2, 1)
        ACC1(wc.x, c0 + 2, 2) ACC1(wc.y, c0 + 3, 0) ACC1(wc.z, c0 + 3, 1) ACC1(wc.w, c0 + 3, 2)
      }
      #undef ACC1
      h1[(t0 + 0) * CCH + c] = fmaxf(a0, 0.f);
      h1[(t0 + 1) * CCH + c] = fmaxf(a1, 0.f);
      h1[(t0 + 2) * CCH + c] = fmaxf(a2, 0.f);
      h1[(t0 + 3) * CCH + c] = fmaxf(a3, 0.f);
    }
  } else {
    int g = (b - 64) * 512 + tid;
    const int GS = 192 * 512;
    for (int idx = g; idx < 768 * 256; idx += GS) { int i = idx >> 8, c = idx & 255; w2t[idx] = w2[c * 768 + i]; }
    for (int idx = g; idx < 768 * CCEP; idx += GS) { int i = idx / CCEP, c = idx - i * CCEP; w3t[idx] = w3[c * 768 + i]; }
  }
}

// ---- K2: conv2 -> conv3 -> FFT/LTV -> OLA+postfilter, flag-synced dataflow ----
__global__ __launch_bounds__(512, 1) void pipe_k(const float* __restrict__ h1, const float* __restrict__ w2t,
                                                 const float* __restrict__ w3t, const float* __restrict__ b2,
                                                 const float* __restrict__ b3, const float* __restrict__ quef,
                                                 const float* __restrict__ z, const float* __restrict__ win,
                                                 const float* __restrict__ pf_w, const float* __restrict__ pf_b,
                                                 float* __restrict__ h2p, float* __restrict__ ccp,
                                                 float* __restrict__ outw, float* __restrict__ y,
                                                 int* __restrict__ flags) {
  int* f1 = flags;        // [64]  conv2 group counters (-> 4)
  int* f2 = flags + 64;   // [64]  conv3 group counters (-> 4)
  int* f3 = flags + 128;  // [256] fftltv frame flags   (-> 1)
  const int b = blockIdx.x, tid = threadIdx.x;
  const int g = b >> 2, kc = b & 3, t0 = g << 2, cbase = kc << 6;
  __shared__ float smem[2048];  // 8 KB, aliased per phase

  // ================= phase A: conv2 split-K partials =================
  {
    float* hs = smem;  // [6][64]
    for (int i = tid; i < 384; i += 512) {
      int r = i >> 6, cin = i & 63;
      int tt = t0 - 1 + r;
      hs[i] = (tt >= 0 && tt < T_FRAMES) ? h1[tt * CCH + cbase + cin] : 0.f;
    }
    __syncthreads();
    {
      int c = tid & 255;
      int th = (tid >> 8) * 2;  // 0 or 2
      const float* hsA = hs + th * 64;
      float a0 = 0.f, a1 = 0.f;
      int i = cbase * 3;
      for (int cin = 0; cin < 64; ++cin) {
        #pragma unroll
        for (int k = 0; k < 3; ++k, ++i) {
          float w = w2t[i * 256 + c];
          a0 += hsA[(k + 0) * 64 + cin] * w;
          a1 += hsA[(k + 1) * 64 + cin] * w;
        }
      }
      int ob = kc << 8;
      h2p[(ob + t0 + th + 0) * CCH + c] = a0;
      h2p[(ob + t0 + th + 1) * CCH + c] = a1;
    }
    __threadfence();
    __syncthreads();
    if (tid == 0) atomicAdd(&f1[g], 1);
  }

  // ================= phase B: conv3 split-K partials =================
  {
    if (tid == 0) {
      int glo = (g == 0) ? 0 : g - 1;
      int ghi = (g == 63) ? 63 : g + 1;
      for (int gg = glo; gg <= ghi; ++gg)
        while (atomicAdd(&f1[gg], 0) < 4) __builtin_amdgcn_s_sleep(2);
    }
    __syncthreads();
    __threadfence();  // acquire: invalidate stale L1/L2 before reading partners' h2p
    float* hs = smem;
    for (int i = tid; i < 384; i += 512) {
      int r = i >> 6, cin = i & 63;
      int tt = t0 - 1 + r;
      float v = 0.f;
      if (tt >= 0 && tt < T_FRAMES) {
        int idx = tt * CCH + cbase + cin;
        v = b2[cbase + cin] + h2p[idx] + h2p[65536 + idx] + h2p[131072 + idx] + h2p[196608 + idx];
        v = fmaxf(v, 0.f);
      }
      hs[i] = v;
    }
    __syncthreads();
    {
      int c = -1, th = 0;
      if (tid < CCEP) { c = tid; th = 0; }
      else if (tid >= 256 && tid < 256 + CCEP) { c = tid - 256; th = 2; }
      if (c >= 0) {
        const float* hsA = hs + th * 64;
        float a0 = 0.f, a1 = 0.f;
        int i = cbase * 3;
        for (int cin = 0; cin < 64; ++cin) {
          #pragma unroll
          for (int k = 0; k < 3; ++k, ++i) {
            float w = w3t[i * CCEP + c];
            a0 += hsA[(k + 0) * 64 + cin] * w;
            a1 += hsA[(k + 1) * 64 + cin] * w;
          }
        }
        int ob = kc << 8;
        ccp[(ob + t0 + th + 0) * CCEP + c] = a0;
        ccp[(ob + t0 + th + 1) * CCEP + c] = a1;
      }
    }
    __threadfence();
    __syncthreads();
    if (tid == 0) atomicAdd(&f2[g], 1);
  }

  // ================= phase C: FFT/spectral/IFFT/LTV for frame t = b =================
  {
    if (tid == 0) {
      while (atomicAdd(&f2[g], 0) < 4) __builtin_amdgcn_s_sleep(2);
    }
    __syncthreads();
    __threadfence();
    float2* U = (float2*)smem;  // [1024]
    int t = b;
    for (int i = tid; i < FFT_N; i += 512) {
      unsigned q = br10((unsigned)i);
      float a = 0.f, bv = 0.f;
      if (q >= 401u && q < 623u) {
        int cq = (int)(q - 401u);
        int base = t * CCEP + cq;
        a = (b3[cq] + ccp[base] + ccp[256 * CCEP + base] + ccp[512 * CCEP + base] + ccp[768 * CCEP + base]) / quef[cq];
      }
      if (q < 512u) {
        int idx = t * HOP + (int)q - 255;
        bv = (idx >= 0 && idx < ZLEN) ? z[idx] : 0.f;
      }
      U[i] = make_float2(a, bv);
    }
    __syncthreads();
    #pragma unroll
    for (int s = 1; s <= 10; ++s) {
      int half = 1 << (s - 1);
      int pos = tid & (half - 1);
      int i1 = ((tid >> (s - 1)) << s) + pos;
      int i2 = i1 + half;
      float ang = (-6.283185307179586f / (float)(1 << s)) * (float)pos;
      float sn, cs; __sincosf(ang, &sn, &cs);
      float2 v2 = U[i2], v1 = U[i1];
      float tr = cs * v2.x - sn * v2.y;
      float ti = cs * v2.y + sn * v2.x;
      U[i1] = make_float2(v1.x + tr, v1.y + ti);
      U[i2] = make_float2(v1.x - tr, v1.y - ti);
      __syncthreads();
    }
    {
      int j = tid;
      int mj = (FFT_N - j) & (FFT_N - 1);
      float2 Uj = U[j], Um = U[mj];
      float2 U5j = make_float2(0.f, 0.f);
      if (tid == 0) U5j = U[512];
      auto pcalc = [](float2 Uj, float2 Um) -> float2 {
        float Ar = 0.5f * (Uj.x + Um.x);
        float Ai = 0.5f * (Uj.y - Um.y);
        float Bx = 0.5f * (Uj.y + Um.y);
        float By = 0.5f * (Um.x - Uj.x);
        float mag = __expf(0.23025850929940457f * Ar);
        float sn, cs; __sincosf(Ai, &sn, &cs);
        float SPx = mag * cs, SPy = mag * sn;
        return make_float2(Bx * SPx + By * SPy, Bx * SPy - By * SPx);
      };
      float2 Pj = pcalc(Uj, Um);
      float2 P5 = (tid == 0) ? pcalc(U5j, U5j) : make_float2(0.f, 0.f);
      __syncthreads();
      U[j] = Pj;
      if (tid == 0) U[512] = P5;
      else U[mj] = make_float2(Pj.x, -Pj.y);
    }
    __syncthreads();
    #pragma unroll
    for (int s = 10; s >= 1; --s) {
      int half = 1 << (s - 1);
      int pos = tid & (half - 1);
      int i1 = ((tid >> (s - 1)) << s) + pos;
      int i2 = i1 + half;
      float ang = (6.283185307179586f / (float)(1 << s)) * (float)pos;
      float sn, cs; __sincosf(ang, &sn, &cs);
      float2 v1 = U[i1], v2 = U[i2];
      U[i1] = make_float2(v1.x + v2.x, v1.y + v2.y);
      float dr = v1.x - v2.x, di = v1.y - v2.y;
      U[i2] = make_float2(cs * dr - sn * di, cs * di + sn * dr);
      __syncthreads();
    }
    const float inv = 1.0f / (float)FFT_N;
    for (int i = tid; i < FFT_N; i += 512) {
      unsigned m = br10((unsigned)i);
      if (m < 512u) {
        int w = 511 - (int)m;
        outw[t * WINL + w] = U[i].x * inv * win[w];
      }
    }
    __threadfence();
    __syncthreads();
    if (tid == 0) atomicAdd(&f3[b], 1);
  }

  // ================= phase D: overlap-add + 128-tap postfilter, chunk b =================
  {
    if (tid == 0) {
      #pragma unroll
      for (int d = -2; d <= 1; ++d) {
        int tt = (b + d) & 255;
        while (atomicAdd(&f3[tt], 0) < 1) __builtin_amdgcn_s_sleep(2);
      }
    }
    __syncthreads();
    __threadfence();
    float* sb = smem;          // [383]
    float* wpf = smem + 384;   // [128]
    int n0 = b * 256;
    for (int i = tid; i < 256 + PF_KT - 1; i += 512) {
      int m = n0 - 63 + i;
      float v = 0.f;
      if (m >= 0 && m < ZLEN) {
        int t = m >> 8, j = m & 255;
        v = outw[t * WINL + j] + outw[((t - 1) & 255) * WINL + HOP + j];
      }
      sb[i] = v;
    }
    if (tid < PF_KT) wpf[tid] = pf_w[tid];
    __syncthreads();
    if (tid < 256) {
      float acc = pf_b[0];
      #pragma unroll 8
      for (int j = 0; j < PF_KT; ++j) acc += sb[tid + j] * wpf[j];
      y[n0 + tid] = acc;
    }
  }
}

extern "C" void kernel_launch(void* const* d_in, const int* in_sizes, int n_in,
                              void* d_out, int out_size, void* d_ws, size_t ws_size,
                              hipStream_t stream) {
  const float* x    = (const float*)d_in[0];
  const float* z    = (const float*)d_in[1];
  const float* w1   = (const float*)d_in[2];
  const float* b1   = (const float*)d_in[3];
  const float* w2   = (const float*)d_in[4];
  const float* b2   = (const float*)d_in[5];
  const float* w3   = (const float*)d_in[6];
  const float* b3   = (const float*)d_in[7];
  const float* pf_w = (const float*)d_in[8];
  const float* pf_b = (const float*)d_in[9];
  const float* quef = (const float*)d_in[10];
  const float* win  = (const float*)d_in[11];
  float* out = (float*)d_out;
  float* ws  = (float*)d_ws;

  // workspace layout (floats)
  float* w2t  = ws;                 // 768*256   = 196608
  float* w3t  = w2t + 196608;       // 768*222   = 170496
  float* h1   = w3t + 170496;       // 256*256   = 65536
  float* h2p  = h1 + 65536;         // 4*256*256 = 262144
  float* ccp  = h2p + 262144;       // 4*256*222 = 227328
  float* outw = ccp + 227328;       // 256*512   = 131072
  int*   flags = (int*)(outw + 131072);  // 384 ints

  conv1_tr_k<<<256, 512, 0, stream>>>(x, w1, b1, w2, w3, h1, w2t, w3t, flags);
  pipe_k<<<256, 512, 0, stream>>>(h1, w2t, w3t, b2, b3, quef, z, win, pf_w, pf_b,
                                  h2p, ccp, outw, out, flags);
}

// Round 7
// 81.994 us; speedup vs baseline: 3.1850x; 3.1850x over previous
//
#include <hip/hip_runtime.h>

#define T_FRAMES 256
#define D_IN 80
#define CCH 256
#define CCEP 222
#define FFT_N 1024
#define HOP 256
#define WINL 512
#define PF_KT 128
#define ZLEN 65536

__device__ __forceinline__ unsigned br10(unsigned x) { return __brev(x) >> 22; }

// ---- K_A: conv1+conv2+conv3 fused, zero cross-block deps via halo recompute ----
// block (g = b>>2, kc = b&3): writes ccp partial for frames 4g..4g+3, cin chunk kc.
__global__ __launch_bounds__(512) void convs_k(const float* __restrict__ x, const float* __restrict__ w1,
                                               const float* __restrict__ b1, const float* __restrict__ w2,
                                               const float* __restrict__ b2, const float* __restrict__ w3,
                                               float* __restrict__ ccp) {
  __shared__ float xs[10 * D_IN];   // x frames t0-3 .. t0+6
  __shared__ float h1s[8 * CCH];    // h1 frames t0-2 .. t0+5
  __shared__ float h2s[6 * 64];     // h2 frames t0-1 .. t0+4, ch chunk
  const int b = blockIdx.x, tid = threadIdx.x;
  const int g = b >> 2, kc = b & 3, t0 = g << 2, cbase = kc << 6;

  // stage x halo (10 frames x 80, zero-padded)
  for (int i = tid; i < 10 * D_IN; i += 512) {
    int r = i / D_IN, cin = i - r * D_IN;
    int tt = t0 - 3 + r;
    xs[i] = (tt >= 0 && tt < T_FRAMES) ? x[tt * D_IN + cin] : 0.f;
  }
  __syncthreads();

  // phase 1: conv1 for 8 frames x 256 ch. thread: c = tid&255, frame-quad fq = tid>>8
  {
    int c = tid & 255;
    int fq = (tid >> 8) << 2;  // 0 or 4
    const float4* row4 = (const float4*)(w1 + c * 240);
    float bb = b1[c];
    float a0 = bb, a1 = bb, a2 = bb, a3 = bb;
    #define ACC1(wv, cin, kk) { float _w = (wv); const float* _xb = xs + ((kk) + fq) * D_IN + (cin); \
      a0 += _xb[0 * D_IN] * _w; a1 += _xb[1 * D_IN] * _w; a2 += _xb[2 * D_IN] * _w; a3 += _xb[3 * D_IN] * _w; }
    #pragma unroll 5
    for (int gg = 0; gg < 20; ++gg) {
      int c0 = gg * 4;
      float4 wa = row4[gg * 3 + 0];
      float4 wb = row4[gg * 3 + 1];
      float4 wc = row4[gg * 3 + 2];
      ACC1(wa.x, c0 + 0, 0) ACC1(wa.y, c0 + 0, 1) ACC1(wa.z, c0 + 0, 2) ACC1(wa.w, c0 + 1, 0)
      ACC1(wb.x, c0 + 1, 1) ACC1(wb.y, c0 + 1, 2) ACC1(wb.z, c0 + 2, 0) ACC1(wb.w, c0 + 2, 1)
      ACC1(wc.x, c0 + 2, 2) ACC1(wc.y, c0 + 3, 0) ACC1(wc.z, c0 + 3, 1) ACC1(wc.w, c0 + 3, 2)
    }
    #undef ACC1
    // frame fi = fq+j corresponds to tt = t0-2+fi; out-of-range -> 0
    float acc[4] = { a0, a1, a2, a3 };
    #pragma unroll
    for (int j = 0; j < 4; ++j) {
      int tt = t0 - 2 + fq + j;
      h1s[(fq + j) * CCH + c] = (tt >= 0 && tt < T_FRAMES) ? fmaxf(acc[j], 0.f) : 0.f;
    }
  }
  __syncthreads();

  // phase 2: conv2 (all 256 cin) for out-ch chunk [cbase,cbase+64), 6 frames. 384 active threads.
  if (tid < 384) {
    int co = tid & 63, fi = tid >> 6;      // fi 0..5, tt = t0-1+fi
    int tt = t0 - 1 + fi;
    float v = 0.f;
    if (tt >= 0 && tt < T_FRAMES) {
      int cog = cbase + co;
      const float4* row4 = (const float4*)(w2 + cog * 768);
      float acc = b2[cog];
      const float* h1b = h1s + fi * CCH;   // h1 frame (tt-1+k) rel index = fi+k
      #pragma unroll 4
      for (int gg = 0; gg < 64; ++gg) {    // 4 cin per group
        int c0 = gg * 4;
        float4 wa = row4[gg * 3 + 0];
        float4 wb = row4[gg * 3 + 1];
        float4 wc = row4[gg * 3 + 2];
        acc += h1b[0 * CCH + c0 + 0] * wa.x + h1b[1 * CCH + c0 + 0] * wa.y + h1b[2 * CCH + c0 + 0] * wa.z;
        acc += h1b[0 * CCH + c0 + 1] * wa.w + h1b[1 * CCH + c0 + 1] * wb.x + h1b[2 * CCH + c0 + 1] * wb.y;
        acc += h1b[0 * CCH + c0 + 2] * wb.z + h1b[1 * CCH + c0 + 2] * wb.w + h1b[2 * CCH + c0 + 2] * wc.x;
        acc += h1b[0 * CCH + c0 + 3] * wc.y + h1b[1 * CCH + c0 + 3] * wc.z + h1b[2 * CCH + c0 + 3] * wc.w;
      }
      v = fmaxf(acc, 0.f);
    }
    h2s[fi * 64 + co] = v;
  }
  __syncthreads();

  // phase 3: conv3 partial from cin chunk. 888 items = 4 frames x 222 oc.
  for (int item = tid; item < 4 * CCEP; item += 512) {
    int fi = item / CCEP, oc = item - fi * CCEP;  // tt = t0+fi
    const float4* row4 = (const float4*)(w3 + oc * 768 + cbase * 3);  // 192 floats
    float acc = 0.f;
    const float* h2b = h2s + fi * 64;  // h2 frame (tt-1+k) rel = fi+k
    #pragma unroll 4
    for (int gg = 0; gg < 16; ++gg) {  // 4 cin per group
      int c0 = gg * 4;
      float4 wa = row4[gg * 3 + 0];
      float4 wb = row4[gg * 3 + 1];
      float4 wc = row4[gg * 3 + 2];
      acc += h2b[0 * 64 + c0 + 0] * wa.x + h2b[1 * 64 + c0 + 0] * wa.y + h2b[2 * 64 + c0 + 0] * wa.z;
      acc += h2b[0 * 64 + c0 + 1] * wa.w + h2b[1 * 64 + c0 + 1] * wb.x + h2b[2 * 64 + c0 + 1] * wb.y;
      acc += h2b[0 * 64 + c0 + 2] * wb.z + h2b[1 * 64 + c0 + 2] * wb.w + h2b[2 * 64 + c0 + 2] * wc.x;
      acc += h2b[0 * 64 + c0 + 3] * wc.y + h2b[1 * 64 + c0 + 3] * wc.z + h2b[2 * 64 + c0 + 3] * wc.w;
    }
    ccp[((kc << 8) + t0 + fi) * CCEP + oc] = acc;
  }
}

// ---- K_B: fused spectral kernel (correlation theorem, one fwd + one inv FFT) ----
__global__ __launch_bounds__(512) void fftltv_k(const float* __restrict__ ccp, const float* __restrict__ b3,
                                                const float* __restrict__ quef, const float* __restrict__ z,
                                                const float* __restrict__ win, float* __restrict__ outw) {
  __shared__ float2 U[FFT_N];
  int t = blockIdx.x, tid = threadIdx.x;
  for (int i = tid; i < FFT_N; i += 512) {
    unsigned q = br10((unsigned)i);
    float a = 0.f, bv = 0.f;
    if (q >= 401u && q < 623u) {
      int cq = (int)(q - 401u);
      int base = t * CCEP + cq;
      a = (b3[cq] + ccp[base] + ccp[256 * CCEP + base] + ccp[512 * CCEP + base] + ccp[768 * CCEP + base]) / quef[cq];
    }
    if (q < 512u) {
      int idx = t * HOP + (int)q - 255;
      bv = (idx >= 0 && idx < ZLEN) ? z[idx] : 0.f;
    }
    U[i] = make_float2(a, bv);
  }
  __syncthreads();
  #pragma unroll
  for (int s = 1; s <= 10; ++s) {
    int half = 1 << (s - 1);
    int pos = tid & (half - 1);
    int i1 = ((tid >> (s - 1)) << s) + pos;
    int i2 = i1 + half;
    float ang = (-6.283185307179586f / (float)(1 << s)) * (float)pos;
    float sn, cs; __sincosf(ang, &sn, &cs);
    float2 v2 = U[i2], v1 = U[i1];
    float tr = cs * v2.x - sn * v2.y;
    float ti = cs * v2.y + sn * v2.x;
    U[i1] = make_float2(v1.x + tr, v1.y + ti);
    U[i2] = make_float2(v1.x - tr, v1.y - ti);
    __syncthreads();
  }
  {
    int j = tid;
    int mj = (FFT_N - j) & (FFT_N - 1);
    float2 Uj = U[j], Um = U[mj];
    float2 U5j = make_float2(0.f, 0.f);
    if (tid == 0) U5j = U[512];
    auto pcalc = [](float2 Uj, float2 Um) -> float2 {
      float Ar = 0.5f * (Uj.x + Um.x);
      float Ai = 0.5f * (Uj.y - Um.y);
      float Bx = 0.5f * (Uj.y + Um.y);
      float By = 0.5f * (Um.x - Uj.x);
      float mag = __expf(0.23025850929940457f * Ar);
      float sn, cs; __sincosf(Ai, &sn, &cs);
      float SPx = mag * cs, SPy = mag * sn;
      return make_float2(Bx * SPx + By * SPy, Bx * SPy - By * SPx);
    };
    float2 Pj = pcalc(Uj, Um);
    float2 P5 = (tid == 0) ? pcalc(U5j, U5j) : make_float2(0.f, 0.f);
    __syncthreads();
    U[j] = Pj;
    if (tid == 0) U[512] = P5;
    else U[mj] = make_float2(Pj.x, -Pj.y);
  }
  __syncthreads();
  #pragma unroll
  for (int s = 10; s >= 1; --s) {
    int half = 1 << (s - 1);
    int pos = tid & (half - 1);
    int i1 = ((tid >> (s - 1)) << s) + pos;
    int i2 = i1 + half;
    float ang = (6.283185307179586f / (float)(1 << s)) * (float)pos;
    float sn, cs; __sincosf(ang, &sn, &cs);
    float2 v1 = U[i1], v2 = U[i2];
    U[i1] = make_float2(v1.x + v2.x, v1.y + v2.y);
    float dr = v1.x - v2.x, di = v1.y - v2.y;
    U[i2] = make_float2(cs * dr - sn * di, cs * di + sn * dr);
    __syncthreads();
  }
  const float inv = 1.0f / (float)FFT_N;
  for (int i = tid; i < FFT_N; i += 512) {
    unsigned m = br10((unsigned)i);
    if (m < 512u) {
      int w = 511 - (int)m;
      outw[t * WINL + w] = U[i].x * inv * win[w];
    }
  }
}

// ---- K_C: overlap-add (circular roll over t) + 128-tap postfilter ----
__global__ __launch_bounds__(256) void pf_k(const float* __restrict__ outw, const float* __restrict__ pf_w,
                                            const float* __restrict__ pf_b, float* __restrict__ y) {
  __shared__ float sb[256 + PF_KT - 1];
  __shared__ float wpf[PF_KT];
  int n0 = blockIdx.x * 256;
  for (int i = threadIdx.x; i < 256 + PF_KT - 1; i += 256) {
    int m = n0 - 63 + i;
    float v = 0.f;
    if (m >= 0 && m < ZLEN) {
      int t = m >> 8, j = m & 255;
      v = outw[t * WINL + j] + outw[((t - 1) & 255) * WINL + HOP + j];
    }
    sb[i] = v;
  }
  if (threadIdx.x < PF_KT) wpf[threadIdx.x] = pf_w[threadIdx.x];
  __syncthreads();
  float acc = pf_b[0];
  #pragma unroll 8
  for (int j = 0; j < PF_KT; ++j) acc += sb[threadIdx.x + j] * wpf[j];
  y[n0 + threadIdx.x] = acc;
}

extern "C" void kernel_launch(void* const* d_in, const int* in_sizes, int n_in,
                              void* d_out, int out_size, void* d_ws, size_t ws_size,
                              hipStream_t stream) {
  const float* x    = (const float*)d_in[0];
  const float* z    = (const float*)d_in[1];
  const float* w1   = (const float*)d_in[2];
  const float* b1   = (const float*)d_in[3];
  const float* w2   = (const float*)d_in[4];
  const float* b2   = (const float*)d_in[5];
  const float* w3   = (const float*)d_in[6];
  const float* b3   = (const float*)d_in[7];
  const float* pf_w = (const float*)d_in[8];
  const float* pf_b = (const float*)d_in[9];
  const float* quef = (const float*)d_in[10];
  const float* win  = (const float*)d_in[11];
  float* out = (float*)d_out;
  float* ws  = (float*)d_ws;

  // workspace layout (floats)
  float* ccp  = ws;                 // 4*256*222 = 227328
  float* outw = ccp + 227328;       // 256*512   = 131072

  convs_k<<<256, 512, 0, stream>>>(x, w1, b1, w2, b2, w3, ccp);
  fftltv_k<<<T_FRAMES, 512, 0, stream>>>(ccp, b3, quef, z, win, outw);
  pf_k<<<ZLEN / 256, 256, 0, stream>>>(outw, pf_w, pf_b, out);
}